// Round 5
// baseline (676.500 us; speedup 1.0000x reference)
//
#include <hip/hip_runtime.h>

typedef __attribute__((ext_vector_type(8))) short bf16x8;
typedef __attribute__((ext_vector_type(4))) float f32x4;

#define T_SEQ 2048
#define EXPM10 4.5399929762484854e-05f  // exp(-10)

__device__ __forceinline__ unsigned short f2bf(float f) {
    unsigned int u = __builtin_bit_cast(unsigned int, f);
    u += 0x7fffu + ((u >> 16) & 1u);
    return (unsigned short)(u >> 16);
}
__device__ __forceinline__ float bf2f(unsigned short u) {
    return __builtin_bit_cast(float, (unsigned int)u << 16);
}

__device__ __forceinline__ void async16(void* lds, const void* g) {
    __builtin_amdgcn_global_load_lds(
        (__attribute__((address_space(1))) void*)g,
        (__attribute__((address_space(3))) void*)lds, 16, 0, 0);
}

// fp32 -> bf16, 4 elems/thread (x activation)
__global__ __launch_bounds__(256) void cvt_bf16(const float* __restrict__ src,
                                                unsigned short* __restrict__ dst, int n4) {
    int i = blockIdx.x * 256 + threadIdx.x;
    if (i < n4) {
        float4 v = ((const float4*)src)[i];
        ushort4 r;
        r.x = f2bf(v.x); r.y = f2bf(v.y); r.z = f2bf(v.z); r.w = f2bf(v.w);
        ((ushort4*)dst)[i] = r;
    }
}

// all 4 weight matrices in one dispatch: wq/wk/wv -> contiguous wqkv, wo -> wob
__global__ __launch_bounds__(256) void cvt_w(const float* __restrict__ wq,
                                             const float* __restrict__ wk,
                                             const float* __restrict__ wv,
                                             const float* __restrict__ wo,
                                             unsigned short* __restrict__ wqkv,
                                             unsigned short* __restrict__ wob) {
    int which = blockIdx.x >> 10;
    int i = (blockIdx.x & 1023) * 256 + threadIdx.x;
    const float* src = which == 0 ? wq : which == 1 ? wk : which == 2 ? wv : wo;
    unsigned short* dst = which < 3 ? wqkv + (size_t)which * 1048576 : wob;
    float4 v = ((const float4*)src)[i];
    ushort4 r;
    r.x = f2bf(v.x); r.y = f2bf(v.y); r.z = f2bf(v.z); r.w = f2bf(v.w);
    ((ushort4*)dst)[i] = r;
}

// Fused QKV projection, BK=64 two-stage staging.
// out[m][n] = sum_k x[m][k]*wqkv[n][k], M=8192, N=3072, K=1024.
__global__ __launch_bounds__(256) void gemm_qkv(const unsigned short* __restrict__ A,
                                                const unsigned short* __restrict__ B,
                                                unsigned short* __restrict__ Qb,
                                                unsigned short* __restrict__ Kb,
                                                unsigned short* __restrict__ Vtb) {
    __shared__ unsigned short As[2][4096];
    __shared__ unsigned short Bs[2][4096];
    const int K = 1024;
    int m0 = blockIdx.y * 128, n0 = blockIdx.x * 128;
    int tid = threadIdx.x;
    int wave = tid >> 6, lane = tid & 63;
    int r = lane & 15, q = lane >> 4;
    int wr = wave >> 1, wc = wave & 1;

    f32x4 acc[4][4];
#pragma unroll
    for (int i = 0; i < 4; i++)
#pragma unroll
        for (int j = 0; j < 4; j++) acc[i][j] = (f32x4){0.f, 0.f, 0.f, 0.f};

    for (int k0 = 0; k0 < K; k0 += 64) {
#pragma unroll
        for (int s = 0; s < 2; s++)
#pragma unroll
            for (int i = 0; i < 2; i++) {
                int li = i * 256 + tid;
                int rw = li >> 2, kc = (li & 3) << 3;
                async16(&As[s][i * 2048 + wave * 512], &A[(size_t)(m0 + rw) * K + k0 + s * 32 + kc]);
                async16(&Bs[s][i * 2048 + wave * 512], &B[(size_t)(n0 + rw) * K + k0 + s * 32 + kc]);
            }
        __syncthreads();
#pragma unroll
        for (int s = 0; s < 2; s++) {
            bf16x8 af[4], bfr[4];
#pragma unroll
            for (int mi = 0; mi < 4; mi++)
                af[mi] = *(const bf16x8*)&As[s][(wr * 64 + mi * 16 + r) * 32 + q * 8];
#pragma unroll
            for (int ni = 0; ni < 4; ni++)
                bfr[ni] = *(const bf16x8*)&Bs[s][(wc * 64 + ni * 16 + r) * 32 + q * 8];
#pragma unroll
            for (int mi = 0; mi < 4; mi++)
#pragma unroll
                for (int ni = 0; ni < 4; ni++)
                    acc[mi][ni] = __builtin_amdgcn_mfma_f32_16x16x32_bf16(
                        af[mi], bfr[ni], acc[mi][ni], 0, 0, 0);
        }
        __syncthreads();
    }

#pragma unroll
    for (int mi = 0; mi < 4; mi++) {
#pragma unroll
        for (int ni = 0; ni < 4; ni++) {
#pragma unroll
            for (int rr = 0; rr < 4; rr++) {
                int gm = m0 + wr * 64 + mi * 16 + q * 4 + rr;
                int gn = n0 + wc * 64 + ni * 16 + r;
                float v = acc[mi][ni][rr];
                int b = gm >> 11, t = gm & 2047;
                int sel = gn >> 10, nn = gn & 1023;
                int h = nn >> 6, d = nn & 63;
                if (sel == 0)
                    Qb[((size_t)(b * 16 + h) * 2048 + t) * 64 + d] = f2bf(v);
                else if (sel == 1)
                    Kb[((size_t)(b * 16 + h) * 2048 + t) * 64 + d] = f2bf(v);
                else
                    Vtb[((size_t)(b * 16 + h) * 64 + d) * 2048 + t] = f2bf(v);
            }
        }
    }
}

// Final projection, BK=64: out[m][n] = sum_k Y[m][k]*wo[n][k], fp32 out.
__global__ __launch_bounds__(256) void gemm_out(const unsigned short* __restrict__ A,
                                                const unsigned short* __restrict__ B,
                                                float* __restrict__ out) {
    __shared__ unsigned short As[2][4096];
    __shared__ unsigned short Bs[2][4096];
    const int K = 1024;
    int m0 = blockIdx.y * 128, n0 = blockIdx.x * 128;
    int tid = threadIdx.x;
    int wave = tid >> 6, lane = tid & 63;
    int r = lane & 15, q = lane >> 4;
    int wr = wave >> 1, wc = wave & 1;

    f32x4 acc[4][4];
#pragma unroll
    for (int i = 0; i < 4; i++)
#pragma unroll
        for (int j = 0; j < 4; j++) acc[i][j] = (f32x4){0.f, 0.f, 0.f, 0.f};

    for (int k0 = 0; k0 < K; k0 += 64) {
#pragma unroll
        for (int s = 0; s < 2; s++)
#pragma unroll
            for (int i = 0; i < 2; i++) {
                int li = i * 256 + tid;
                int rw = li >> 2, kc = (li & 3) << 3;
                async16(&As[s][i * 2048 + wave * 512], &A[(size_t)(m0 + rw) * K + k0 + s * 32 + kc]);
                async16(&Bs[s][i * 2048 + wave * 512], &B[(size_t)(n0 + rw) * K + k0 + s * 32 + kc]);
            }
        __syncthreads();
#pragma unroll
        for (int s = 0; s < 2; s++) {
            bf16x8 af[4], bfr[4];
#pragma unroll
            for (int mi = 0; mi < 4; mi++)
                af[mi] = *(const bf16x8*)&As[s][(wr * 64 + mi * 16 + r) * 32 + q * 8];
#pragma unroll
            for (int ni = 0; ni < 4; ni++)
                bfr[ni] = *(const bf16x8*)&Bs[s][(wc * 64 + ni * 16 + r) * 32 + q * 8];
#pragma unroll
            for (int mi = 0; mi < 4; mi++)
#pragma unroll
                for (int ni = 0; ni < 4; ni++)
                    acc[mi][ni] = __builtin_amdgcn_mfma_f32_16x16x32_bf16(
                        af[mi], bfr[ni], acc[mi][ni], 0, 0, 0);
        }
        __syncthreads();
    }

#pragma unroll
    for (int mi = 0; mi < 4; mi++)
#pragma unroll
        for (int ni = 0; ni < 4; ni++)
#pragma unroll
            for (int rr = 0; rr < 4; rr++) {
                int gm = m0 + wr * 64 + mi * 16 + q * 4 + rr;
                int gn = n0 + wc * 64 + ni * 16 + r;
                out[(size_t)gm * 1024 + gn] = acc[mi][ni][rr];
            }
}

// Suffix sums of V at 64-key granularity: SV[bh][j][d] = sum_{k >= 64j} V[bh][k][d]
__global__ __launch_bounds__(256) void suffix_sv(const unsigned short* __restrict__ Vt,
                                                 float* __restrict__ SV) {
    __shared__ float bsum[32][64];
    int bh = blockIdx.x;
    int d = threadIdx.x & 63, c = threadIdx.x >> 6;
    const unsigned short* base = Vt + ((size_t)bh * 64 + d) * T_SEQ;
#pragma unroll
    for (int jj = 0; jj < 8; jj++) {
        int j = c * 8 + jj;
        float s = 0.f;
#pragma unroll
        for (int t8 = 0; t8 < 8; t8++) {
            bf16x8 v = *(const bf16x8*)(base + j * 64 + t8 * 8);
#pragma unroll
            for (int e = 0; e < 8; e++) s += bf2f((unsigned short)v[e]);
        }
        bsum[j][d] = s;
    }
    __syncthreads();
    if (threadIdx.x < 64) {
        float run = 0.f;
        for (int j = 31; j >= 0; j--) {
            run += bsum[j][d];
            SV[((size_t)bh * 32 + j) * 64 + d] = run;
        }
    }
}

// Barrier-free flash attention. Each WAVE independently owns one 16-query strip
// (strip s = 4g + wave; queries 16s..16s+15) and streams key tiles 0..g.
// K-frags and V-frags are 16B-contiguous in global memory in exact MFMA operand
// layout (K head-major [t][d], V transposed [d][t]) -> direct global_load_dwordx4,
// NO LDS staging, NO __syncthreads. Only the wave-private P C-layout -> A-layout
// transform round-trips through 9 KB of LDS.
// Masking: strips align to 64-tiles so only the final tile (it==g) needs the
// explicit -10 fill; keys >= 64(g+1) are folded analytically via SV suffix sums
// (valid because masked logits are exactly -10 and no-max softmax is in use).
#define PST 72
__global__ __launch_bounds__(256) void attn(const unsigned short* __restrict__ Q,
                                            const unsigned short* __restrict__ Kg,
                                            const unsigned short* __restrict__ Vt,
                                            const float* __restrict__ SV,
                                            unsigned short* __restrict__ Y) {
    __shared__ unsigned short Ps[4][16 * PST];  // per wave: [query r][key]
    int bh = blockIdx.y;
    int g = 31 - blockIdx.x;  // heavy strips dispatch first
    int tid = threadIdx.x, wave = tid >> 6, lane = tid & 63;
    int r = lane & 15, qd = lane >> 4;
    int s = 4 * g + wave;
    int query = 16 * s + r;

    const unsigned short* qptr = Q + ((size_t)bh * T_SEQ + query) * 64 + qd * 8;
    bf16x8 qf0 = *(const bf16x8*)qptr;
    bf16x8 qf1 = *(const bf16x8*)(qptr + 32);

    const unsigned short* kbase = Kg + (size_t)bh * T_SEQ * 64;   // [key][d]
    const unsigned short* vbase = Vt + (size_t)bh * 64 * T_SEQ;   // [d][key]
    const float scale = 0.125f;

    float l_lane = 0.f;
    f32x4 o[4];
#pragma unroll
    for (int n = 0; n < 4; n++) o[n] = (f32x4){0.f, 0.f, 0.f, 0.f};

    for (int it = 0; it <= g; ++it) {
        int k0 = it * 64;
        // S^T = K Q^T : K-frags straight from global (A-operand layout)
        f32x4 st[4];
#pragma unroll
        for (int t = 0; t < 4; t++) {
            const unsigned short* kp = kbase + (size_t)(k0 + t * 16 + r) * 64 + qd * 8;
            bf16x8 kf0 = *(const bf16x8*)kp;
            bf16x8 kf1 = *(const bf16x8*)(kp + 32);
            st[t] = (f32x4){0.f, 0.f, 0.f, 0.f};
            st[t] = __builtin_amdgcn_mfma_f32_16x16x32_bf16(kf0, qf0, st[t], 0, 0, 0);
            st[t] = __builtin_amdgcn_mfma_f32_16x16x32_bf16(kf1, qf1, st[t], 0, 0, 0);
        }

        // p = exp(logit); mask only possible in the final tile (it == g)
        float sum = 0.f;
        if (it == g) {
#pragma unroll
            for (int t = 0; t < 4; t++) {
                float p[4];
#pragma unroll
                for (int e = 0; e < 4; e++) {
                    int kgidx = k0 + t * 16 + qd * 4 + e;
                    float pe = __expf(st[t][e] * scale);
                    p[e] = (kgidx <= query) ? pe : EXPM10;
                    sum += p[e];
                }
                ushort4 pk;
                pk.x = f2bf(p[0]); pk.y = f2bf(p[1]); pk.z = f2bf(p[2]); pk.w = f2bf(p[3]);
                *(ushort4*)&Ps[wave][r * PST + t * 16 + qd * 4] = pk;
            }
        } else {
#pragma unroll
            for (int t = 0; t < 4; t++) {
                float p[4];
#pragma unroll
                for (int e = 0; e < 4; e++) { p[e] = __expf(st[t][e] * scale); sum += p[e]; }
                ushort4 pk;
                pk.x = f2bf(p[0]); pk.y = f2bf(p[1]); pk.z = f2bf(p[2]); pk.w = f2bf(p[3]);
                *(ushort4*)&Ps[wave][r * PST + t * 16 + qd * 4] = pk;
            }
        }
        l_lane += sum;
        __builtin_amdgcn_sched_barrier(0);  // wave-private Ps: keep write->read order

        // O^T += V * P^T : V-frags straight from global (A-operand layout)
        bf16x8 pf0 = *(const bf16x8*)&Ps[wave][r * PST + qd * 8];
        bf16x8 pf1 = *(const bf16x8*)&Ps[wave][r * PST + 32 + qd * 8];
#pragma unroll
        for (int n = 0; n < 4; n++) {
            const unsigned short* vp = vbase + (size_t)(n * 16 + r) * T_SEQ + k0 + qd * 8;
            bf16x8 vf0 = *(const bf16x8*)vp;
            bf16x8 vf1 = *(const bf16x8*)(vp + 32);
            o[n] = __builtin_amdgcn_mfma_f32_16x16x32_bf16(vf0, pf0, o[n], 0, 0, 0);
            o[n] = __builtin_amdgcn_mfma_f32_16x16x32_bf16(vf1, pf1, o[n], 0, 0, 0);
        }
    }

    // reduce l across the 4 qd-groups (disjoint key subsets per lane)
    float l_i = l_lane;
    l_i += __shfl_xor(l_i, 16);
    l_i += __shfl_xor(l_i, 32);

    // analytic tail: keys >= 64(g+1) all have logit exactly -10
    int j = g + 1;
    float pm = 0.f, tail_l = 0.f;
    float sv[4][4];
#pragma unroll
    for (int n = 0; n < 4; n++)
#pragma unroll
        for (int e = 0; e < 4; e++) sv[n][e] = 0.f;
    if (j < 32) {
        pm = EXPM10;
        tail_l = (float)(T_SEQ - 64 * j) * pm;
        const float* svp = SV + ((size_t)bh * 32 + j) * 64;
#pragma unroll
        for (int n = 0; n < 4; n++) {
            float4 f = *(const float4*)(svp + n * 16 + qd * 4);
            sv[n][0] = f.x; sv[n][1] = f.y; sv[n][2] = f.z; sv[n][3] = f.w;
        }
    }
    float inv = 1.0f / (l_i + tail_l);
    int b = bh >> 4, h = bh & 15;
#pragma unroll
    for (int n = 0; n < 4; n++) {
        ushort4 yk;
        yk.x = f2bf((o[n][0] + pm * sv[n][0]) * inv);
        yk.y = f2bf((o[n][1] + pm * sv[n][1]) * inv);
        yk.z = f2bf((o[n][2] + pm * sv[n][2]) * inv);
        yk.w = f2bf((o[n][3] + pm * sv[n][3]) * inv);
        *(ushort4*)&Y[(((size_t)b * T_SEQ + query) * 16 + h) * 64 + n * 16 + qd * 4] = yk;
    }
}

extern "C" void kernel_launch(void* const* d_in, const int* in_sizes, int n_in,
                              void* d_out, int out_size, void* d_ws, size_t ws_size,
                              hipStream_t stream) {
    const float* x  = (const float*)d_in[0];
    const float* wq = (const float*)d_in[1];
    const float* wk = (const float*)d_in[2];
    const float* wv = (const float*)d_in[3];
    const float* wo = (const float*)d_in[4];

    char* ws = (char*)d_ws;
    const size_t MB = 1u << 20;
    unsigned short* xb   = (unsigned short*)(ws);            // 16 MB (reused as Yb)
    unsigned short* Qb   = (unsigned short*)(ws + 16 * MB);  // 16 MB
    unsigned short* Kb   = (unsigned short*)(ws + 32 * MB);  // 16 MB
    unsigned short* Vtb  = (unsigned short*)(ws + 48 * MB);  // 16 MB
    unsigned short* wqkv = (unsigned short*)(ws + 64 * MB);  // 6 MB
    unsigned short* wob  = (unsigned short*)(ws + 70 * MB);  // 2 MB -> 72 MB total
    unsigned short* Yb   = xb;
    float* SVf = (float*)d_out;  // scratch until final gemm overwrites d_out

    cvt_bf16<<<8192, 256, 0, stream>>>(x, xb, 2097152);
    cvt_w<<<4096, 256, 0, stream>>>(wq, wk, wv, wo, wqkv, wob);

    gemm_qkv<<<dim3(24, 64), 256, 0, stream>>>(xb, wqkv, Qb, Kb, Vtb);

    suffix_sv<<<64, 256, 0, stream>>>(Vtb, SVf);

    attn<<<dim3(32, 64), 256, 0, stream>>>(Qb, Kb, Vtb, SVf, Yb);

    gemm_out<<<dim3(8, 64), 256, 0, stream>>>(Yb, wob, (float*)d_out);
}

// Round 6
// 310.322 us; speedup vs baseline: 2.1800x; 2.1800x over previous
//
#include <hip/hip_runtime.h>

typedef __attribute__((ext_vector_type(8))) short bf16x8;
typedef __attribute__((ext_vector_type(4))) float f32x4;

#define T_SEQ 2048
#define EXPM10 4.5399929762484854e-05f  // exp(-10)

__device__ __forceinline__ unsigned short f2bf(float f) {
    unsigned int u = __builtin_bit_cast(unsigned int, f);
    u += 0x7fffu + ((u >> 16) & 1u);
    return (unsigned short)(u >> 16);
}
__device__ __forceinline__ float bf2f(unsigned short u) {
    return __builtin_bit_cast(float, (unsigned int)u << 16);
}

__device__ __forceinline__ void async16(void* lds, const void* g) {
    __builtin_amdgcn_global_load_lds(
        (__attribute__((address_space(1))) void*)g,
        (__attribute__((address_space(3))) void*)lds, 16, 0, 0);
}

// fp32 -> bf16, 4 elems/thread (x activation)
__global__ __launch_bounds__(256) void cvt_bf16(const float* __restrict__ src,
                                                unsigned short* __restrict__ dst, int n4) {
    int i = blockIdx.x * 256 + threadIdx.x;
    if (i < n4) {
        float4 v = ((const float4*)src)[i];
        ushort4 r;
        r.x = f2bf(v.x); r.y = f2bf(v.y); r.z = f2bf(v.z); r.w = f2bf(v.w);
        ((ushort4*)dst)[i] = r;
    }
}

// all 4 weight matrices in one dispatch: wq/wk/wv -> contiguous wqkv, wo -> wob
__global__ __launch_bounds__(256) void cvt_w(const float* __restrict__ wq,
                                             const float* __restrict__ wk,
                                             const float* __restrict__ wv,
                                             const float* __restrict__ wo,
                                             unsigned short* __restrict__ wqkv,
                                             unsigned short* __restrict__ wob) {
    int which = blockIdx.x >> 10;
    int i = (blockIdx.x & 1023) * 256 + threadIdx.x;
    const float* src = which == 0 ? wq : which == 1 ? wk : which == 2 ? wv : wo;
    unsigned short* dst = which < 3 ? wqkv + (size_t)which * 1048576 : wob;
    float4 v = ((const float4*)src)[i];
    ushort4 r;
    r.x = f2bf(v.x); r.y = f2bf(v.y); r.z = f2bf(v.z); r.w = f2bf(v.w);
    ((ushort4*)dst)[i] = r;
}

// Fused QKV projection, BK=64 two-stage staging.
// out[m][n] = sum_k x[m][k]*wqkv[n][k], M=8192, N=3072, K=1024.
__global__ __launch_bounds__(256) void gemm_qkv(const unsigned short* __restrict__ A,
                                                const unsigned short* __restrict__ B,
                                                unsigned short* __restrict__ Qb,
                                                unsigned short* __restrict__ Kb,
                                                unsigned short* __restrict__ Vtb) {
    __shared__ unsigned short As[2][4096];
    __shared__ unsigned short Bs[2][4096];
    const int K = 1024;
    int m0 = blockIdx.y * 128, n0 = blockIdx.x * 128;
    int tid = threadIdx.x;
    int wave = tid >> 6, lane = tid & 63;
    int r = lane & 15, q = lane >> 4;
    int wr = wave >> 1, wc = wave & 1;

    f32x4 acc[4][4];
#pragma unroll
    for (int i = 0; i < 4; i++)
#pragma unroll
        for (int j = 0; j < 4; j++) acc[i][j] = (f32x4){0.f, 0.f, 0.f, 0.f};

    for (int k0 = 0; k0 < K; k0 += 64) {
#pragma unroll
        for (int s = 0; s < 2; s++)
#pragma unroll
            for (int i = 0; i < 2; i++) {
                int li = i * 256 + tid;
                int rw = li >> 2, kc = (li & 3) << 3;
                async16(&As[s][i * 2048 + wave * 512], &A[(size_t)(m0 + rw) * K + k0 + s * 32 + kc]);
                async16(&Bs[s][i * 2048 + wave * 512], &B[(size_t)(n0 + rw) * K + k0 + s * 32 + kc]);
            }
        __syncthreads();
#pragma unroll
        for (int s = 0; s < 2; s++) {
            bf16x8 af[4], bfr[4];
#pragma unroll
            for (int mi = 0; mi < 4; mi++)
                af[mi] = *(const bf16x8*)&As[s][(wr * 64 + mi * 16 + r) * 32 + q * 8];
#pragma unroll
            for (int ni = 0; ni < 4; ni++)
                bfr[ni] = *(const bf16x8*)&Bs[s][(wc * 64 + ni * 16 + r) * 32 + q * 8];
#pragma unroll
            for (int mi = 0; mi < 4; mi++)
#pragma unroll
                for (int ni = 0; ni < 4; ni++)
                    acc[mi][ni] = __builtin_amdgcn_mfma_f32_16x16x32_bf16(
                        af[mi], bfr[ni], acc[mi][ni], 0, 0, 0);
        }
        __syncthreads();
    }

#pragma unroll
    for (int mi = 0; mi < 4; mi++) {
#pragma unroll
        for (int ni = 0; ni < 4; ni++) {
#pragma unroll
            for (int rr = 0; rr < 4; rr++) {
                int gm = m0 + wr * 64 + mi * 16 + q * 4 + rr;
                int gn = n0 + wc * 64 + ni * 16 + r;
                float v = acc[mi][ni][rr];
                int b = gm >> 11, t = gm & 2047;
                int sel = gn >> 10, nn = gn & 1023;
                int h = nn >> 6, d = nn & 63;
                if (sel == 0)
                    Qb[((size_t)(b * 16 + h) * 2048 + t) * 64 + d] = f2bf(v);
                else if (sel == 1)
                    Kb[((size_t)(b * 16 + h) * 2048 + t) * 64 + d] = f2bf(v);
                else
                    Vtb[((size_t)(b * 16 + h) * 64 + d) * 2048 + t] = f2bf(v);
            }
        }
    }
}

// Final projection, BK=64: out[m][n] = sum_k Y[m][k]*wo[n][k], fp32 out.
__global__ __launch_bounds__(256) void gemm_out(const unsigned short* __restrict__ A,
                                                const unsigned short* __restrict__ B,
                                                float* __restrict__ out) {
    __shared__ unsigned short As[2][4096];
    __shared__ unsigned short Bs[2][4096];
    const int K = 1024;
    int m0 = blockIdx.y * 128, n0 = blockIdx.x * 128;
    int tid = threadIdx.x;
    int wave = tid >> 6, lane = tid & 63;
    int r = lane & 15, q = lane >> 4;
    int wr = wave >> 1, wc = wave & 1;

    f32x4 acc[4][4];
#pragma unroll
    for (int i = 0; i < 4; i++)
#pragma unroll
        for (int j = 0; j < 4; j++) acc[i][j] = (f32x4){0.f, 0.f, 0.f, 0.f};

    for (int k0 = 0; k0 < K; k0 += 64) {
#pragma unroll
        for (int s = 0; s < 2; s++)
#pragma unroll
            for (int i = 0; i < 2; i++) {
                int li = i * 256 + tid;
                int rw = li >> 2, kc = (li & 3) << 3;
                async16(&As[s][i * 2048 + wave * 512], &A[(size_t)(m0 + rw) * K + k0 + s * 32 + kc]);
                async16(&Bs[s][i * 2048 + wave * 512], &B[(size_t)(n0 + rw) * K + k0 + s * 32 + kc]);
            }
        __syncthreads();
#pragma unroll
        for (int s = 0; s < 2; s++) {
            bf16x8 af[4], bfr[4];
#pragma unroll
            for (int mi = 0; mi < 4; mi++)
                af[mi] = *(const bf16x8*)&As[s][(wr * 64 + mi * 16 + r) * 32 + q * 8];
#pragma unroll
            for (int ni = 0; ni < 4; ni++)
                bfr[ni] = *(const bf16x8*)&Bs[s][(wc * 64 + ni * 16 + r) * 32 + q * 8];
#pragma unroll
            for (int mi = 0; mi < 4; mi++)
#pragma unroll
                for (int ni = 0; ni < 4; ni++)
                    acc[mi][ni] = __builtin_amdgcn_mfma_f32_16x16x32_bf16(
                        af[mi], bfr[ni], acc[mi][ni], 0, 0, 0);
        }
        __syncthreads();
    }

#pragma unroll
    for (int mi = 0; mi < 4; mi++)
#pragma unroll
        for (int ni = 0; ni < 4; ni++)
#pragma unroll
            for (int rr = 0; rr < 4; rr++) {
                int gm = m0 + wr * 64 + mi * 16 + q * 4 + rr;
                int gn = n0 + wc * 64 + ni * 16 + r;
                out[(size_t)gm * 1024 + gn] = acc[mi][ni][rr];
            }
}

// Suffix sums of V at 64-key granularity: SV[bh][j][d] = sum_{k >= 64j} V[bh][k][d]
__global__ __launch_bounds__(256) void suffix_sv(const unsigned short* __restrict__ Vt,
                                                 float* __restrict__ SV) {
    __shared__ float bsum[32][64];
    int bh = blockIdx.x;
    int d = threadIdx.x & 63, c = threadIdx.x >> 6;
    const unsigned short* base = Vt + ((size_t)bh * 64 + d) * T_SEQ;
#pragma unroll
    for (int jj = 0; jj < 8; jj++) {
        int j = c * 8 + jj;
        float s = 0.f;
#pragma unroll
        for (int t8 = 0; t8 < 8; t8++) {
            bf16x8 v = *(const bf16x8*)(base + j * 64 + t8 * 8);
#pragma unroll
            for (int e = 0; e < 8; e++) s += bf2f((unsigned short)v[e]);
        }
        bsum[j][d] = s;
    }
    __syncthreads();
    if (threadIdx.x < 64) {
        float run = 0.f;
        for (int j = 31; j >= 0; j--) {
            run += bsum[j][d];
            SV[((size_t)bh * 32 + j) * 64 + d] = run;
        }
    }
}

// Flash attention, transposed-S, no-max softmax, analytic -10 tail (R3 inner
// structure), with UNIFORM LOAD BALANCE: each block processes two 64-query
// tiles sequentially -- qi = 16+bx (heavy: 17..32 key-tiles) then 15-bx
// (light: 16..1) -- so every block runs exactly 33 tile-iters + 2 epilogues.
// Grid 16x64 = 1024 identical blocks -> sustained ~4 blocks/CU, no tail skew.
#define KST 72
#define VST 72
#define PST 72
__global__ __launch_bounds__(256) void attn(const unsigned short* __restrict__ Q,
                                            const unsigned short* __restrict__ Kg,
                                            const unsigned short* __restrict__ Vt,
                                            const float* __restrict__ SV,
                                            unsigned short* __restrict__ Y) {
    __shared__ unsigned short Ks[64 * KST];    // [key][d]
    __shared__ unsigned short Vs[64 * VST];    // [d][key]
    __shared__ unsigned short Ps[4][16 * PST]; // per wave: [query][key]
    int bh = blockIdx.y;
    int tid = threadIdx.x, wave = tid >> 6, lane = tid & 63;
    int r = lane & 15, qd = lane >> 4;
    int b = bh >> 4, h = bh & 15;

    int srow = tid >> 2, scol = (tid & 3) * 16;  // staging: 64 rows x 128B
    const unsigned short* kg = Kg + ((size_t)bh * T_SEQ + srow) * 64 + scol;
    const unsigned short* vg = Vt + ((size_t)bh * 64 + srow) * T_SEQ + scol;
    const float scale = 0.125f;

#pragma unroll
    for (int phase = 0; phase < 2; phase++) {
        int qi = phase == 0 ? 16 + (int)blockIdx.x : 15 - (int)blockIdx.x;
        int q0 = qi * 64;
        int query = q0 + wave * 16 + r;

        const unsigned short* qptr = Q + ((size_t)bh * T_SEQ + query) * 64 + qd * 8;
        bf16x8 qf0 = *(const bf16x8*)qptr;
        bf16x8 qf1 = *(const bf16x8*)(qptr + 32);

        float l_lane = 0.0f;
        f32x4 o[4];
#pragma unroll
        for (int n = 0; n < 4; n++) o[n] = (f32x4){0.f, 0.f, 0.f, 0.f};

        // prefetch tile 0 into registers
        bf16x8 pk0 = *(const bf16x8*)(kg);
        bf16x8 pk1 = *(const bf16x8*)(kg + 8);
        bf16x8 pv0 = *(const bf16x8*)(vg);
        bf16x8 pv1 = *(const bf16x8*)(vg + 8);

        int iters = qi + 1;
        for (int it = 0; it < iters; ++it) {
            __syncthreads();  // all waves done reading Ks/Vs of previous tile
            *(bf16x8*)&Ks[srow * KST + scol]     = pk0;
            *(bf16x8*)&Ks[srow * KST + scol + 8] = pk1;
            *(bf16x8*)&Vs[srow * VST + scol]     = pv0;
            *(bf16x8*)&Vs[srow * VST + scol + 8] = pv1;
            __syncthreads();
            // issue next tile's loads now; latency hidden behind compute
            if (it + 1 < iters) {
                size_t kn = (size_t)(it + 1) * 64;
                pk0 = *(const bf16x8*)(kg + kn * 64);
                pk1 = *(const bf16x8*)(kg + kn * 64 + 8);
                pv0 = *(const bf16x8*)(vg + kn);
                pv1 = *(const bf16x8*)(vg + kn + 8);
            }

            int k0 = it * 64;
            f32x4 st[4];
#pragma unroll
            for (int t = 0; t < 4; t++) {
                bf16x8 kf0 = *(const bf16x8*)&Ks[(t * 16 + r) * KST + qd * 8];
                bf16x8 kf1 = *(const bf16x8*)&Ks[(t * 16 + r) * KST + 32 + qd * 8];
                st[t] = (f32x4){0.f, 0.f, 0.f, 0.f};
                st[t] = __builtin_amdgcn_mfma_f32_16x16x32_bf16(kf0, qf0, st[t], 0, 0, 0);
                st[t] = __builtin_amdgcn_mfma_f32_16x16x32_bf16(kf1, qf1, st[t], 0, 0, 0);
            }

            // p = exp(logit); masked -> exp(-10) const. No max-tracking.
            float p[4][4], sum = 0.f;
            bool anymask = (k0 + 63 > q0 + wave * 16);  // wave-uniform
            if (anymask) {
#pragma unroll
                for (int t = 0; t < 4; t++)
#pragma unroll
                    for (int e = 0; e < 4; e++) {
                        int kgidx = k0 + t * 16 + qd * 4 + e;
                        float pe = __expf(st[t][e] * scale);
                        p[t][e] = (kgidx <= query) ? pe : EXPM10;
                        sum += p[t][e];
                    }
            } else {
#pragma unroll
                for (int t = 0; t < 4; t++)
#pragma unroll
                    for (int e = 0; e < 4; e++) {
                        p[t][e] = __expf(st[t][e] * scale);
                        sum += p[t][e];
                    }
            }
            l_lane += sum;

            // pack P -> per-wave LDS [query][key]
#pragma unroll
            for (int t = 0; t < 4; t++) {
                ushort4 pk;
                pk.x = f2bf(p[t][0]); pk.y = f2bf(p[t][1]);
                pk.z = f2bf(p[t][2]); pk.w = f2bf(p[t][3]);
                *(ushort4*)&Ps[wave][r * PST + t * 16 + qd * 4] = pk;
            }
            __builtin_amdgcn_sched_barrier(0);  // wave-private Ps: keep order

            // O^T += V * P^T
            bf16x8 pf0 = *(const bf16x8*)&Ps[wave][r * PST + qd * 8];
            bf16x8 pf1 = *(const bf16x8*)&Ps[wave][r * PST + 32 + qd * 8];
#pragma unroll
            for (int n = 0; n < 4; n++) {
                bf16x8 vf0 = *(const bf16x8*)&Vs[(n * 16 + r) * VST + qd * 8];
                bf16x8 vf1 = *(const bf16x8*)&Vs[(n * 16 + r) * VST + 32 + qd * 8];
                o[n] = __builtin_amdgcn_mfma_f32_16x16x32_bf16(vf0, pf0, o[n], 0, 0, 0);
                o[n] = __builtin_amdgcn_mfma_f32_16x16x32_bf16(vf1, pf1, o[n], 0, 0, 0);
            }
        }

        // reduce l across the 4 qd-groups (disjoint key subsets per lane)
        float l_i = l_lane;
        l_i += __shfl_xor(l_i, 16);
        l_i += __shfl_xor(l_i, 32);

        // analytic tail: keys >= q0+64 all have logit exactly -10
        int j = qi + 1;
        float pm = 0.f, tail_l = 0.f;
        float sv[4][4];
#pragma unroll
        for (int n = 0; n < 4; n++)
#pragma unroll
            for (int e = 0; e < 4; e++) sv[n][e] = 0.f;
        if (j < 32) {
            pm = EXPM10;
            tail_l = (float)(T_SEQ - 64 * j) * pm;
            const float* svp = SV + ((size_t)bh * 32 + j) * 64;
#pragma unroll
            for (int n = 0; n < 4; n++) {
                float4 f = *(const float4*)(svp + n * 16 + qd * 4);
                sv[n][0] = f.x; sv[n][1] = f.y; sv[n][2] = f.z; sv[n][3] = f.w;
            }
        }
        float inv = 1.0f / (l_i + tail_l);
#pragma unroll
        for (int n = 0; n < 4; n++) {
            ushort4 yk;
            yk.x = f2bf((o[n][0] + pm * sv[n][0]) * inv);
            yk.y = f2bf((o[n][1] + pm * sv[n][1]) * inv);
            yk.z = f2bf((o[n][2] + pm * sv[n][2]) * inv);
            yk.w = f2bf((o[n][3] + pm * sv[n][3]) * inv);
            *(ushort4*)&Y[(((size_t)b * T_SEQ + query) * 16 + h) * 64 + n * 16 + qd * 4] = yk;
        }
    }
}

extern "C" void kernel_launch(void* const* d_in, const int* in_sizes, int n_in,
                              void* d_out, int out_size, void* d_ws, size_t ws_size,
                              hipStream_t stream) {
    const float* x  = (const float*)d_in[0];
    const float* wq = (const float*)d_in[1];
    const float* wk = (const float*)d_in[2];
    const float* wv = (const float*)d_in[3];
    const float* wo = (const float*)d_in[4];

    char* ws = (char*)d_ws;
    const size_t MB = 1u << 20;
    unsigned short* xb   = (unsigned short*)(ws);            // 16 MB (reused as Yb)
    unsigned short* Qb   = (unsigned short*)(ws + 16 * MB);  // 16 MB
    unsigned short* Kb   = (unsigned short*)(ws + 32 * MB);  // 16 MB
    unsigned short* Vtb  = (unsigned short*)(ws + 48 * MB);  // 16 MB
    unsigned short* wqkv = (unsigned short*)(ws + 64 * MB);  // 6 MB
    unsigned short* wob  = (unsigned short*)(ws + 70 * MB);  // 2 MB -> 72 MB total
    unsigned short* Yb   = xb;
    float* SVf = (float*)d_out;  // scratch until final gemm overwrites d_out

    cvt_bf16<<<8192, 256, 0, stream>>>(x, xb, 2097152);
    cvt_w<<<4096, 256, 0, stream>>>(wq, wk, wv, wo, wqkv, wob);

    gemm_qkv<<<dim3(24, 64), 256, 0, stream>>>(xb, wqkv, Qb, Kb, Vtb);

    suffix_sv<<<64, 256, 0, stream>>>(Vtb, SVf);

    attn<<<dim3(16, 64), 256, 0, stream>>>(Qb, Kb, Vtb, SVf, Yb);

    gemm_out<<<dim3(8, 64), 256, 0, stream>>>(Yb, wob, (float*)d_out);
}

// Round 7
// 305.735 us; speedup vs baseline: 2.2127x; 1.0150x over previous
//
#include <hip/hip_runtime.h>

typedef __attribute__((ext_vector_type(8))) short bf16x8;
typedef __attribute__((ext_vector_type(4))) float f32x4;

#define T_SEQ 2048
#define EXPM10 4.5399929762484854e-05f  // exp(-10)

// s_waitcnt imm (gfx9 encoding): vmcnt[3:0] | expcnt<<4 | lgkmcnt<<8
#define WAIT_VM4 0xF74  // vmcnt(4), expcnt/lgkm no-wait
#define WAIT_VM0 0xF70  // vmcnt(0)

__device__ __forceinline__ unsigned short f2bf(float f) {
    unsigned int u = __builtin_bit_cast(unsigned int, f);
    u += 0x7fffu + ((u >> 16) & 1u);
    return (unsigned short)(u >> 16);
}
__device__ __forceinline__ float bf2f(unsigned short u) {
    return __builtin_bit_cast(float, (unsigned int)u << 16);
}

__device__ __forceinline__ void async16(void* lds, const void* g) {
    __builtin_amdgcn_global_load_lds(
        (__attribute__((address_space(1))) void*)g,
        (__attribute__((address_space(3))) void*)lds, 16, 0, 0);
}

// fp32 -> bf16, 4 elems/thread (x activation)
__global__ __launch_bounds__(256) void cvt_bf16(const float* __restrict__ src,
                                                unsigned short* __restrict__ dst, int n4) {
    int i = blockIdx.x * 256 + threadIdx.x;
    if (i < n4) {
        float4 v = ((const float4*)src)[i];
        ushort4 r;
        r.x = f2bf(v.x); r.y = f2bf(v.y); r.z = f2bf(v.z); r.w = f2bf(v.w);
        ((ushort4*)dst)[i] = r;
    }
}

// all 4 weight matrices in one dispatch: wq/wk/wv -> contiguous wqkv, wo -> wob
__global__ __launch_bounds__(256) void cvt_w(const float* __restrict__ wq,
                                             const float* __restrict__ wk,
                                             const float* __restrict__ wv,
                                             const float* __restrict__ wo,
                                             unsigned short* __restrict__ wqkv,
                                             unsigned short* __restrict__ wob) {
    int which = blockIdx.x >> 10;
    int i = (blockIdx.x & 1023) * 256 + threadIdx.x;
    const float* src = which == 0 ? wq : which == 1 ? wk : which == 2 ? wv : wo;
    unsigned short* dst = which < 3 ? wqkv + (size_t)which * 1048576 : wob;
    float4 v = ((const float4*)src)[i];
    ushort4 r;
    r.x = f2bf(v.x); r.y = f2bf(v.y); r.z = f2bf(v.z); r.w = f2bf(v.w);
    ((ushort4*)dst)[i] = r;
}

// Fused QKV projection with ASYNC double-buffered K-loop: raw s_barrier +
// s_waitcnt vmcnt(4) keeps next-tile global_load_lds in flight across the
// barrier (the __syncthreads vmcnt(0) drain was the 4x stall at shallow K).
// out[m][n] = sum_k x[m][k]*wqkv[n][k], M=8192, N=3072, K=1024. BK=32.
__global__ __launch_bounds__(256) void gemm_qkv(const unsigned short* __restrict__ A,
                                                const unsigned short* __restrict__ B,
                                                unsigned short* __restrict__ Qb,
                                                unsigned short* __restrict__ Kb,
                                                unsigned short* __restrict__ Vtb) {
    __shared__ unsigned short As[2][4096];  // [buf][128 rows x 32 k]
    __shared__ unsigned short Bs[2][4096];
    const int K = 1024;
    int m0 = blockIdx.y * 128, n0 = blockIdx.x * 128;
    int tid = threadIdx.x;
    int wave = tid >> 6, lane = tid & 63;
    int r = lane & 15, q = lane >> 4;
    int wr = wave >> 1, wc = wave & 1;

    f32x4 acc[4][4];
#pragma unroll
    for (int i = 0; i < 4; i++)
#pragma unroll
        for (int j = 0; j < 4; j++) acc[i][j] = (f32x4){0.f, 0.f, 0.f, 0.f};

    // per-thread staging pointers (rows i*64 + tid>>2, k-offset (tid&3)*8)
    int rw = tid >> 2, kc = (tid & 3) << 3;
    const unsigned short* a0 = A + (size_t)(m0 + rw) * K + kc;
    const unsigned short* a1 = A + (size_t)(m0 + 64 + rw) * K + kc;
    const unsigned short* b0 = B + (size_t)(n0 + rw) * K + kc;
    const unsigned short* b1 = B + (size_t)(n0 + 64 + rw) * K + kc;

    // prologue: issue tile 0 into buf 0 (4 loads/thread)
    async16(&As[0][wave * 512], a0);
    async16(&As[0][2048 + wave * 512], a1);
    async16(&Bs[0][wave * 512], b0);
    async16(&Bs[0][2048 + wave * 512], b1);

    for (int it = 0; it < 32; ++it) {
        // barrier1: all waves done computing it-1 (done reading buf[(it+1)&1])
        __builtin_amdgcn_s_barrier();
        __builtin_amdgcn_sched_barrier(0);
        if (it + 1 < 32) {
            int bn = (it + 1) & 1;
            int ko = (it + 1) * 32;
            async16(&As[bn][wave * 512], a0 + ko);
            async16(&As[bn][2048 + wave * 512], a1 + ko);
            async16(&Bs[bn][wave * 512], b0 + ko);
            async16(&Bs[bn][2048 + wave * 512], b1 + ko);
            __builtin_amdgcn_sched_barrier(0);
            __builtin_amdgcn_s_waitcnt(WAIT_VM4);  // tile it landed (issued 1 iter ago)
        } else {
            __builtin_amdgcn_s_waitcnt(WAIT_VM0);
        }
        // barrier2: every wave confirmed its own tile-it loads -> LDS complete
        __builtin_amdgcn_s_barrier();
        __builtin_amdgcn_sched_barrier(0);

        int bc = it & 1;
        bf16x8 af[4], bfr[4];
#pragma unroll
        for (int mi = 0; mi < 4; mi++)
            af[mi] = *(const bf16x8*)&As[bc][(wr * 64 + mi * 16 + r) * 32 + q * 8];
#pragma unroll
        for (int ni = 0; ni < 4; ni++)
            bfr[ni] = *(const bf16x8*)&Bs[bc][(wc * 64 + ni * 16 + r) * 32 + q * 8];
#pragma unroll
        for (int mi = 0; mi < 4; mi++)
#pragma unroll
            for (int ni = 0; ni < 4; ni++)
                acc[mi][ni] = __builtin_amdgcn_mfma_f32_16x16x32_bf16(
                    af[mi], bfr[ni], acc[mi][ni], 0, 0, 0);
    }

#pragma unroll
    for (int mi = 0; mi < 4; mi++) {
#pragma unroll
        for (int ni = 0; ni < 4; ni++) {
#pragma unroll
            for (int rr = 0; rr < 4; rr++) {
                int gm = m0 + wr * 64 + mi * 16 + q * 4 + rr;
                int gn = n0 + wc * 64 + ni * 16 + r;
                float v = acc[mi][ni][rr];
                int b = gm >> 11, t = gm & 2047;
                int sel = gn >> 10, nn = gn & 1023;
                int h = nn >> 6, d = nn & 63;
                if (sel == 0)
                    Qb[((size_t)(b * 16 + h) * 2048 + t) * 64 + d] = f2bf(v);
                else if (sel == 1)
                    Kb[((size_t)(b * 16 + h) * 2048 + t) * 64 + d] = f2bf(v);
                else
                    Vtb[((size_t)(b * 16 + h) * 64 + d) * 2048 + t] = f2bf(v);
            }
        }
    }
}

// Final projection, same async dbuf K-loop, fp32 out. M=8192,N=1024,K=1024.
__global__ __launch_bounds__(256) void gemm_out(const unsigned short* __restrict__ A,
                                                const unsigned short* __restrict__ B,
                                                float* __restrict__ out) {
    __shared__ unsigned short As[2][4096];
    __shared__ unsigned short Bs[2][4096];
    const int K = 1024;
    int m0 = blockIdx.y * 128, n0 = blockIdx.x * 128;
    int tid = threadIdx.x;
    int wave = tid >> 6, lane = tid & 63;
    int r = lane & 15, q = lane >> 4;
    int wr = wave >> 1, wc = wave & 1;

    f32x4 acc[4][4];
#pragma unroll
    for (int i = 0; i < 4; i++)
#pragma unroll
        for (int j = 0; j < 4; j++) acc[i][j] = (f32x4){0.f, 0.f, 0.f, 0.f};

    int rw = tid >> 2, kc = (tid & 3) << 3;
    const unsigned short* a0 = A + (size_t)(m0 + rw) * K + kc;
    const unsigned short* a1 = A + (size_t)(m0 + 64 + rw) * K + kc;
    const unsigned short* b0 = B + (size_t)(n0 + rw) * K + kc;
    const unsigned short* b1 = B + (size_t)(n0 + 64 + rw) * K + kc;

    async16(&As[0][wave * 512], a0);
    async16(&As[0][2048 + wave * 512], a1);
    async16(&Bs[0][wave * 512], b0);
    async16(&Bs[0][2048 + wave * 512], b1);

    for (int it = 0; it < 32; ++it) {
        __builtin_amdgcn_s_barrier();
        __builtin_amdgcn_sched_barrier(0);
        if (it + 1 < 32) {
            int bn = (it + 1) & 1;
            int ko = (it + 1) * 32;
            async16(&As[bn][wave * 512], a0 + ko);
            async16(&As[bn][2048 + wave * 512], a1 + ko);
            async16(&Bs[bn][wave * 512], b0 + ko);
            async16(&Bs[bn][2048 + wave * 512], b1 + ko);
            __builtin_amdgcn_sched_barrier(0);
            __builtin_amdgcn_s_waitcnt(WAIT_VM4);
        } else {
            __builtin_amdgcn_s_waitcnt(WAIT_VM0);
        }
        __builtin_amdgcn_s_barrier();
        __builtin_amdgcn_sched_barrier(0);

        int bc = it & 1;
        bf16x8 af[4], bfr[4];
#pragma unroll
        for (int mi = 0; mi < 4; mi++)
            af[mi] = *(const bf16x8*)&As[bc][(wr * 64 + mi * 16 + r) * 32 + q * 8];
#pragma unroll
        for (int ni = 0; ni < 4; ni++)
            bfr[ni] = *(const bf16x8*)&Bs[bc][(wc * 64 + ni * 16 + r) * 32 + q * 8];
#pragma unroll
        for (int mi = 0; mi < 4; mi++)
#pragma unroll
            for (int ni = 0; ni < 4; ni++)
                acc[mi][ni] = __builtin_amdgcn_mfma_f32_16x16x32_bf16(
                    af[mi], bfr[ni], acc[mi][ni], 0, 0, 0);
    }

#pragma unroll
    for (int mi = 0; mi < 4; mi++)
#pragma unroll
        for (int ni = 0; ni < 4; ni++)
#pragma unroll
            for (int rr = 0; rr < 4; rr++) {
                int gm = m0 + wr * 64 + mi * 16 + q * 4 + rr;
                int gn = n0 + wc * 64 + ni * 16 + r;
                out[(size_t)gm * 1024 + gn] = acc[mi][ni][rr];
            }
}

// Suffix sums of V at 64-key granularity: SV[bh][j][d] = sum_{k >= 64j} V[bh][k][d]
__global__ __launch_bounds__(256) void suffix_sv(const unsigned short* __restrict__ Vt,
                                                 float* __restrict__ SV) {
    __shared__ float bsum[32][64];
    int bh = blockIdx.x;
    int d = threadIdx.x & 63, c = threadIdx.x >> 6;
    const unsigned short* base = Vt + ((size_t)bh * 64 + d) * T_SEQ;
#pragma unroll
    for (int jj = 0; jj < 8; jj++) {
        int j = c * 8 + jj;
        float s = 0.f;
#pragma unroll
        for (int t8 = 0; t8 < 8; t8++) {
            bf16x8 v = *(const bf16x8*)(base + j * 64 + t8 * 8);
#pragma unroll
            for (int e = 0; e < 8; e++) s += bf2f((unsigned short)v[e]);
        }
        bsum[j][d] = s;
    }
    __syncthreads();
    if (threadIdx.x < 64) {
        float run = 0.f;
        for (int j = 31; j >= 0; j--) {
            run += bsum[j][d];
            SV[((size_t)bh * 32 + j) * 64 + d] = run;
        }
    }
}

// Flash attention (R6 structure, unchanged): transposed-S, no-max softmax,
// analytic -10 tail, register-prefetch staging, 2-phase uniform load balance.
#define KST 72
#define VST 72
#define PST 72
__global__ __launch_bounds__(256) void attn(const unsigned short* __restrict__ Q,
                                            const unsigned short* __restrict__ Kg,
                                            const unsigned short* __restrict__ Vt,
                                            const float* __restrict__ SV,
                                            unsigned short* __restrict__ Y) {
    __shared__ unsigned short Ks[64 * KST];    // [key][d]
    __shared__ unsigned short Vs[64 * VST];    // [d][key]
    __shared__ unsigned short Ps[4][16 * PST]; // per wave: [query][key]
    int bh = blockIdx.y;
    int tid = threadIdx.x, wave = tid >> 6, lane = tid & 63;
    int r = lane & 15, qd = lane >> 4;
    int b = bh >> 4, h = bh & 15;

    int srow = tid >> 2, scol = (tid & 3) * 16;  // staging: 64 rows x 128B
    const unsigned short* kg = Kg + ((size_t)bh * T_SEQ + srow) * 64 + scol;
    const unsigned short* vg = Vt + ((size_t)bh * 64 + srow) * T_SEQ + scol;
    const float scale = 0.125f;

#pragma unroll
    for (int phase = 0; phase < 2; phase++) {
        int qi = phase == 0 ? 16 + (int)blockIdx.x : 15 - (int)blockIdx.x;
        int q0 = qi * 64;
        int query = q0 + wave * 16 + r;

        const unsigned short* qptr = Q + ((size_t)bh * T_SEQ + query) * 64 + qd * 8;
        bf16x8 qf0 = *(const bf16x8*)qptr;
        bf16x8 qf1 = *(const bf16x8*)(qptr + 32);

        float l_lane = 0.0f;
        f32x4 o[4];
#pragma unroll
        for (int n = 0; n < 4; n++) o[n] = (f32x4){0.f, 0.f, 0.f, 0.f};

        bf16x8 pk0 = *(const bf16x8*)(kg);
        bf16x8 pk1 = *(const bf16x8*)(kg + 8);
        bf16x8 pv0 = *(const bf16x8*)(vg);
        bf16x8 pv1 = *(const bf16x8*)(vg + 8);

        int iters = qi + 1;
        for (int it = 0; it < iters; ++it) {
            __syncthreads();
            *(bf16x8*)&Ks[srow * KST + scol]     = pk0;
            *(bf16x8*)&Ks[srow * KST + scol + 8] = pk1;
            *(bf16x8*)&Vs[srow * VST + scol]     = pv0;
            *(bf16x8*)&Vs[srow * VST + scol + 8] = pv1;
            __syncthreads();
            if (it + 1 < iters) {
                size_t kn = (size_t)(it + 1) * 64;
                pk0 = *(const bf16x8*)(kg + kn * 64);
                pk1 = *(const bf16x8*)(kg + kn * 64 + 8);
                pv0 = *(const bf16x8*)(vg + kn);
                pv1 = *(const bf16x8*)(vg + kn + 8);
            }

            int k0 = it * 64;
            f32x4 st[4];
#pragma unroll
            for (int t = 0; t < 4; t++) {
                bf16x8 kf0 = *(const bf16x8*)&Ks[(t * 16 + r) * KST + qd * 8];
                bf16x8 kf1 = *(const bf16x8*)&Ks[(t * 16 + r) * KST + 32 + qd * 8];
                st[t] = (f32x4){0.f, 0.f, 0.f, 0.f};
                st[t] = __builtin_amdgcn_mfma_f32_16x16x32_bf16(kf0, qf0, st[t], 0, 0, 0);
                st[t] = __builtin_amdgcn_mfma_f32_16x16x32_bf16(kf1, qf1, st[t], 0, 0, 0);
            }

            float p[4][4], sum = 0.f;
            bool anymask = (k0 + 63 > q0 + wave * 16);  // wave-uniform
            if (anymask) {
#pragma unroll
                for (int t = 0; t < 4; t++)
#pragma unroll
                    for (int e = 0; e < 4; e++) {
                        int kgidx = k0 + t * 16 + qd * 4 + e;
                        float pe = __expf(st[t][e] * scale);
                        p[t][e] = (kgidx <= query) ? pe : EXPM10;
                        sum += p[t][e];
                    }
            } else {
#pragma unroll
                for (int t = 0; t < 4; t++)
#pragma unroll
                    for (int e = 0; e < 4; e++) {
                        p[t][e] = __expf(st[t][e] * scale);
                        sum += p[t][e];
                    }
            }
            l_lane += sum;

#pragma unroll
            for (int t = 0; t < 4; t++) {
                ushort4 pk;
                pk.x = f2bf(p[t][0]); pk.y = f2bf(p[t][1]);
                pk.z = f2bf(p[t][2]); pk.w = f2bf(p[t][3]);
                *(ushort4*)&Ps[wave][r * PST + t * 16 + qd * 4] = pk;
            }
            __builtin_amdgcn_sched_barrier(0);  // wave-private Ps: keep order

            bf16x8 pf0 = *(const bf16x8*)&Ps[wave][r * PST + qd * 8];
            bf16x8 pf1 = *(const bf16x8*)&Ps[wave][r * PST + 32 + qd * 8];
#pragma unroll
            for (int n = 0; n < 4; n++) {
                bf16x8 vf0 = *(const bf16x8*)&Vs[(n * 16 + r) * VST + qd * 8];
                bf16x8 vf1 = *(const bf16x8*)&Vs[(n * 16 + r) * VST + 32 + qd * 8];
                o[n] = __builtin_amdgcn_mfma_f32_16x16x32_bf16(vf0, pf0, o[n], 0, 0, 0);
                o[n] = __builtin_amdgcn_mfma_f32_16x16x32_bf16(vf1, pf1, o[n], 0, 0, 0);
            }
        }

        float l_i = l_lane;
        l_i += __shfl_xor(l_i, 16);
        l_i += __shfl_xor(l_i, 32);

        int j = qi + 1;
        float pm = 0.f, tail_l = 0.f;
        float sv[4][4];
#pragma unroll
        for (int n = 0; n < 4; n++)
#pragma unroll
            for (int e = 0; e < 4; e++) sv[n][e] = 0.f;
        if (j < 32) {
            pm = EXPM10;
            tail_l = (float)(T_SEQ - 64 * j) * pm;
            const float* svp = SV + ((size_t)bh * 32 + j) * 64;
#pragma unroll
            for (int n = 0; n < 4; n++) {
                float4 f = *(const float4*)(svp + n * 16 + qd * 4);
                sv[n][0] = f.x; sv[n][1] = f.y; sv[n][2] = f.z; sv[n][3] = f.w;
            }
        }
        float inv = 1.0f / (l_i + tail_l);
#pragma unroll
        for (int n = 0; n < 4; n++) {
            ushort4 yk;
            yk.x = f2bf((o[n][0] + pm * sv[n][0]) * inv);
            yk.y = f2bf((o[n][1] + pm * sv[n][1]) * inv);
            yk.z = f2bf((o[n][2] + pm * sv[n][2]) * inv);
            yk.w = f2bf((o[n][3] + pm * sv[n][3]) * inv);
            *(ushort4*)&Y[(((size_t)b * T_SEQ + query) * 16 + h) * 64 + n * 16 + qd * 4] = yk;
        }
    }
}

extern "C" void kernel_launch(void* const* d_in, const int* in_sizes, int n_in,
                              void* d_out, int out_size, void* d_ws, size_t ws_size,
                              hipStream_t stream) {
    const float* x  = (const float*)d_in[0];
    const float* wq = (const float*)d_in[1];
    const float* wk = (const float*)d_in[2];
    const float* wv = (const float*)d_in[3];
    const float* wo = (const float*)d_in[4];

    char* ws = (char*)d_ws;
    const size_t MB = 1u << 20;
    unsigned short* xb   = (unsigned short*)(ws);            // 16 MB (reused as Yb)
    unsigned short* Qb   = (unsigned short*)(ws + 16 * MB);  // 16 MB
    unsigned short* Kb   = (unsigned short*)(ws + 32 * MB);  // 16 MB
    unsigned short* Vtb  = (unsigned short*)(ws + 48 * MB);  // 16 MB
    unsigned short* wqkv = (unsigned short*)(ws + 64 * MB);  // 6 MB
    unsigned short* wob  = (unsigned short*)(ws + 70 * MB);  // 2 MB -> 72 MB total
    unsigned short* Yb   = xb;
    float* SVf = (float*)d_out;  // scratch until final gemm overwrites d_out

    cvt_bf16<<<8192, 256, 0, stream>>>(x, xb, 2097152);
    cvt_w<<<4096, 256, 0, stream>>>(wq, wk, wv, wo, wqkv, wob);

    gemm_qkv<<<dim3(24, 64), 256, 0, stream>>>(xb, wqkv, Qb, Kb, Vtb);

    suffix_sv<<<64, 256, 0, stream>>>(Vtb, SVf);

    attn<<<dim3(16, 64), 256, 0, stream>>>(Qb, Kb, Vtb, SVf, Yb);

    gemm_out<<<dim3(8, 64), 256, 0, stream>>>(Yb, wob, (float*)d_out);
}